// Round 4
// baseline (225.175 us; speedup 1.0000x reference)
//
#include <hip/hip_runtime.h>

#define N_NODES 4096
#define EPS 0.005f
#define TH0 0.4f
#define TH1 0.24f
#define TH2 0.144f
#define TH3 0.0864f
#define JTILE 256
#define NTILES (N_NODES / JTILE)
#define RCAP 80      // fixed per-row slot capacity (mean deg 32, P(>80)~1e-13)
#define CPAD 16      // one counter per 64B line -> no cross-XCD line ping-pong

typedef float v4f __attribute__((ext_vector_type(4)));
typedef unsigned int u32x2 __attribute__((ext_vector_type(2)));

// ws layout (byte offsets):
//   0      counts int[4096*16]         256KB \ one contiguous memset (2816KB)
//   256K   pairs  int2[4096*RCAP]      2.5MB / pads col=0,val=0 -> fma no-op
//   4M     m2     bf16[N*N]            32MB dense thresholded A@A

static __device__ __forceinline__ float lo16(unsigned int u) {
    return __uint_as_float(u << 16);
}
static __device__ __forceinline__ float hi16(unsigned int u) {
    return __uint_as_float(u & 0xffff0000u);
}

static __device__ __forceinline__ unsigned short f2bf(float f) {
    union { float f; unsigned int i; } x;
    x.f = f;
    unsigned int r = x.i + 0x7fff + ((x.i >> 16) & 1u);  // RNE; finite >=0
    return (unsigned short)(r >> 16);
}

// one pass: bin edges into fixed-stride packed (col,val) slots
__global__ void scatter_kernel(const int* __restrict__ idx,
                               const float* __restrict__ attr, int E,
                               int* __restrict__ counts, int2* __restrict__ pairs) {
    int e = blockIdx.x * blockDim.x + threadIdx.x;
    if (e < E) {
        int s = idx[e];
        int d = idx[e + E];
        float a = attr[e];
        int pos = atomicAdd(&counts[s * CPAD], 1);
        if (pos < RCAP) pairs[s * RCAP + pos] = make_int2(d, __float_as_int(a));
    }
}

// M2 = thr(A@A) bf16. One block per row, full-row 16KB LDS accumulator.
// 32 groups x 8 lanes; fan-out list walked in 32-slot rounds of 4 INDEPENDENT
// loads (chain depth 4 -> 1). Slots in [fn,RCAP) are zero-pads -> no-op adds.
__global__ __launch_bounds__(256)
void m2_kernel(const int* __restrict__ counts, const int2* __restrict__ pairs,
               unsigned short* __restrict__ m2) {
    __shared__ float acc[N_NODES];
    __shared__ int   kcol[RCAP];
    __shared__ float kval[RCAP];
    __shared__ int   kcnt[RCAP];
    int i = blockIdx.x;
    int t = threadIdx.x;
    float4 z = make_float4(0.f, 0.f, 0.f, 0.f);
    for (int j4 = t; j4 < N_NODES / 4; j4 += 256) ((float4*)acc)[j4] = z;
    int cnt = min(counts[i * CPAD], RCAP);
    if (t < cnt) {
        int2 p = pairs[i * RCAP + t];
        kcol[t] = p.x;
        kval[t] = __int_as_float(p.y);
        kcnt[t] = min(counts[p.x * CPAD], RCAP);
    }
    __syncthreads();
    int gid = t >> 3, gl = t & 7;            // 32 groups x 8 lanes
    int2 zp = make_int2(0, 0);
    for (int q = gid; q < cnt; q += 32) {
        float a = kval[q];
        int fb = kcol[q] * RCAP;
        int fn = kcnt[q];
        for (int f0 = gl; f0 < fn; f0 += 32) {
            int i1 = f0 + 8, i2 = f0 + 16, i3 = f0 + 24;
            // 4 independent loads issued before any atomic; masked -> (0,0)
            int2 p0 = pairs[fb + f0];
            int2 p1 = (i1 < fn) ? pairs[fb + i1] : zp;
            int2 p2 = (i2 < fn) ? pairs[fb + i2] : zp;
            int2 p3 = (i3 < fn) ? pairs[fb + i3] : zp;
            unsafeAtomicAdd(&acc[p0.x], a * __int_as_float(p0.y));
            unsafeAtomicAdd(&acc[p1.x], a * __int_as_float(p1.y));
            unsafeAtomicAdd(&acc[p2.x], a * __int_as_float(p2.y));
            unsafeAtomicAdd(&acc[p3.x], a * __int_as_float(p3.y));
        }
    }
    __syncthreads();
    size_t rb = (size_t)i * N_NODES;
    for (int j4 = t; j4 < N_NODES / 4; j4 += 256) {
        float4 v = ((const float4*)acc)[j4];
        ushort4 r;
        r.x = (v.x >= EPS) ? f2bf(v.x) : (unsigned short)0;
        r.y = (v.y >= EPS) ? f2bf(v.y) : (unsigned short)0;
        r.z = (v.z >= EPS) ? f2bf(v.z) : (unsigned short)0;
        r.w = (v.w >= EPS) ? f2bf(v.w) : (unsigned short)0;
        ((ushort4*)(m2 + rb))[j4] = r;
    }
}

// out[i, jb:jb+256] = TH0*P0 + TH1*A + TH2*M2 + TH3*thr(A @ M2)  — fused.
// Round-0 structure (proven 71us @ JTILE=512), with the L2 working set halved:
// JTILE=256 -> per-XCD m2 column slice = 2MB (was 4MB == L2 size -> constant
// conflict eviction, FETCH 62MB vs 35MB compulsory, ~900cy stalls).
// Grid time-partition: first 16384 blocks run tiles 0-7 (tile==XCD via %8
// round-robin), second 16384 run tiles 8-15 -> each XCD streams one 2MB slice
// at a time. 2 waves/block = 2 rows, same tile; wave-private LDS strips.
__global__ __launch_bounds__(128)
void out_kernel(const int* __restrict__ counts, const int2* __restrict__ pairs,
                const unsigned short* __restrict__ m2,
                float* __restrict__ out) {
    __shared__ float ap[2][JTILE];
    int lin = blockIdx.x;
    int tile = (lin & 7) | ((lin >> 14) << 3);   // 0-7 first half, 8-15 second
    int jb = tile * JTILE;
    int t = threadIdx.x;
    int w = t >> 6, lane = t & 63;
    int i = 2 * ((lin >> 3) & 2047) + w;
    float* apw = ap[w];
    ((float4*)apw)[lane] = make_float4(0.f, 0.f, 0.f, 0.f);  // 256 floats/wave
    int cnt = min(counts[i * CPAD], RCAP);
    const int2* pi = pairs + i * RCAP;
    // P0 + A scatter into private strip (dups accumulate; cnt excludes pads)
    for (int e = lane; e < cnt; e += 64) {
        int2 p = pi[e];
        int cl = p.x - jb;
        if ((unsigned)cl < (unsigned)JTILE)
            unsafeAtomicAdd(&apw[cl], TH0 + TH1 * __int_as_float(p.y));
    }
    // dense gather over neighbors' m2 row-segments, 8 per iteration, 8B/lane
    int cnt8 = (cnt + 7) & ~7;
    const unsigned short* m2l = m2 + jb + 4 * lane;
    v4f acc0 = 0.f;
    for (int e = 0; e < cnt8; e += 8) {
        int4 q01 = *(const int4*)(pi + e);
        int4 q23 = *(const int4*)(pi + e + 2);
        int4 q45 = *(const int4*)(pi + e + 4);
        int4 q67 = *(const int4*)(pi + e + 6);
        int k0 = __builtin_amdgcn_readfirstlane(q01.x);
        int k1 = __builtin_amdgcn_readfirstlane(q01.z);
        int k2 = __builtin_amdgcn_readfirstlane(q23.x);
        int k3 = __builtin_amdgcn_readfirstlane(q23.z);
        int k4 = __builtin_amdgcn_readfirstlane(q45.x);
        int k5 = __builtin_amdgcn_readfirstlane(q45.z);
        int k6 = __builtin_amdgcn_readfirstlane(q67.x);
        int k7 = __builtin_amdgcn_readfirstlane(q67.z);
        float a0 = __int_as_float(q01.y), a1 = __int_as_float(q01.w);
        float a2 = __int_as_float(q23.y), a3 = __int_as_float(q23.w);
        float a4 = __int_as_float(q45.y), a5 = __int_as_float(q45.w);
        float a6 = __int_as_float(q67.y), a7 = __int_as_float(q67.w);
        u32x2 u0 = *(const u32x2*)(m2l + (size_t)k0 * N_NODES);
        u32x2 u1 = *(const u32x2*)(m2l + (size_t)k1 * N_NODES);
        u32x2 u2 = *(const u32x2*)(m2l + (size_t)k2 * N_NODES);
        u32x2 u3 = *(const u32x2*)(m2l + (size_t)k3 * N_NODES);
        u32x2 u4 = *(const u32x2*)(m2l + (size_t)k4 * N_NODES);
        u32x2 u5 = *(const u32x2*)(m2l + (size_t)k5 * N_NODES);
        u32x2 u6 = *(const u32x2*)(m2l + (size_t)k6 * N_NODES);
        u32x2 u7 = *(const u32x2*)(m2l + (size_t)k7 * N_NODES);
#define ACC4(uu, aa)                                \
        acc0.x = fmaf(aa, lo16(uu.x), acc0.x);      \
        acc0.y = fmaf(aa, hi16(uu.x), acc0.y);      \
        acc0.z = fmaf(aa, lo16(uu.y), acc0.z);      \
        acc0.w = fmaf(aa, hi16(uu.y), acc0.w);
        ACC4(u0, a0) ACC4(u1, a1) ACC4(u2, a2) ACC4(u3, a3)
        ACC4(u4, a4) ACC4(u5, a5) ACC4(u6, a6) ACC4(u7, a7)
#undef ACC4
    }
    // epilogue: private strip + TH2*m2[i] + TH3*thr(acc)
    u32x2 um = *(const u32x2*)(m2 + (size_t)i * N_NODES + jb + 4 * lane);
    float4 p0 = ((const float4*)apw)[lane];
    v4f r0;
    r0.x = p0.x + TH2 * lo16(um.x) + TH3 * ((acc0.x >= EPS) ? acc0.x : 0.0f);
    r0.y = p0.y + TH2 * hi16(um.x) + TH3 * ((acc0.y >= EPS) ? acc0.y : 0.0f);
    r0.z = p0.z + TH2 * lo16(um.y) + TH3 * ((acc0.z >= EPS) ? acc0.z : 0.0f);
    r0.w = p0.w + TH2 * hi16(um.y) + TH3 * ((acc0.w >= EPS) ? acc0.w : 0.0f);
    float* o = out + (size_t)i * N_NODES + jb + 4 * lane;
    __builtin_nontemporal_store(r0, (v4f*)o);
}

extern "C" void kernel_launch(void* const* d_in, const int* in_sizes, int n_in,
                              void* d_out, int out_size, void* d_ws, size_t ws_size,
                              hipStream_t stream) {
    const int* idx = (const int*)d_in[1];     // [2,E] flat: src then dst
    const float* attr = (const float*)d_in[2];
    int E = in_sizes[1] / 2;

    char* ws = (char*)d_ws;
    int*  counts = (int*)(ws);
    int2* pairs  = (int2*)(ws + (256 << 10));
    unsigned short* m2 = (unsigned short*)(ws + (4 << 20));
    float* out   = (float*)d_out;

    // counts (padded) + pairs contiguous: one memset
    (void)hipMemsetAsync(ws, 0,
                         (256 << 10) + N_NODES * RCAP * sizeof(int2), stream);
    scatter_kernel<<<(E + 255) / 256, 256, 0, stream>>>(idx, attr, E, counts, pairs);
    m2_kernel<<<N_NODES, 256, 0, stream>>>(counts, pairs, m2);
    out_kernel<<<(N_NODES / 2) * NTILES, 128, 0, stream>>>(counts, pairs, m2, out);
}

// Round 7
// 207.360 us; speedup vs baseline: 1.0859x; 1.0859x over previous
//
#include <hip/hip_runtime.h>

#define N_NODES 4096
#define EPS 0.005f
#define TH0 0.4f
#define TH1 0.24f
#define TH2 0.144f
#define TH3 0.0864f
#define JTILE 512
#define NTILES (N_NODES / JTILE)
#define RCAP 80      // fixed per-row slot capacity (mean deg 32, P(>80)~1e-13)
#define CPAD 16      // one counter per 64B line -> no cross-XCD line ping-pong

typedef float v4f __attribute__((ext_vector_type(4)));
typedef unsigned int u32x4 __attribute__((ext_vector_type(4)));

// ws layout (byte offsets):
//   0      counts int[4096*16]         256KB \ one contiguous memset (2816KB)
//   256K   pairs  int2[4096*RCAP]      2.5MB / pads col=0,val=0 -> fma no-op
//   4M     m2     bf16[N*N]            32MB dense thresholded A@A
// All pair reads are clamped inside the memset region (no garbage values
// ever enter registers; R6's unclamped variant failed correctness).

static __device__ __forceinline__ float lo16(unsigned int u) {
    return __uint_as_float(u << 16);
}
static __device__ __forceinline__ float hi16(unsigned int u) {
    return __uint_as_float(u & 0xffff0000u);
}

static __device__ __forceinline__ unsigned short f2bf(float f) {
    union { float f; unsigned int i; } x;
    x.f = f;
    unsigned int r = x.i + 0x7fff + ((x.i >> 16) & 1u);  // RNE; finite >=0
    return (unsigned short)(r >> 16);
}

// one pass: bin edges into fixed-stride packed (col,val) slots
__global__ void scatter_kernel(const int* __restrict__ idx,
                               const float* __restrict__ attr, int E,
                               int* __restrict__ counts, int2* __restrict__ pairs) {
    int e = blockIdx.x * blockDim.x + threadIdx.x;
    if (e < E) {
        int s = idx[e];
        int d = idx[e + E];
        float a = attr[e];
        int pos = atomicAdd(&counts[s * CPAD], 1);
        if (pos < RCAP) pairs[s * RCAP + pos] = make_int2(d, __float_as_int(a));
    }
}

// M2 = thr(A@A) bf16. One block per row, full-row 16KB LDS accumulator.
// 32 groups x 8 lanes; fan-out list walked in 32-slot rounds of 4 INDEPENDENT
// loads (chain depth 4 -> 1). Slots in [fn,RCAP) are zero-pads -> no-op adds.
__global__ __launch_bounds__(256)
void m2_kernel(const int* __restrict__ counts, const int2* __restrict__ pairs,
               unsigned short* __restrict__ m2) {
    __shared__ float acc[N_NODES];
    __shared__ int   kcol[RCAP];
    __shared__ float kval[RCAP];
    __shared__ int   kcnt[RCAP];
    int i = blockIdx.x;
    int t = threadIdx.x;
    float4 z = make_float4(0.f, 0.f, 0.f, 0.f);
    for (int j4 = t; j4 < N_NODES / 4; j4 += 256) ((float4*)acc)[j4] = z;
    int cnt = min(counts[i * CPAD], RCAP);
    if (t < cnt) {
        int2 p = pairs[i * RCAP + t];
        kcol[t] = p.x;
        kval[t] = __int_as_float(p.y);
        kcnt[t] = min(counts[p.x * CPAD], RCAP);
    }
    __syncthreads();
    int gid = t >> 3, gl = t & 7;            // 32 groups x 8 lanes
    int2 zp = make_int2(0, 0);
    for (int q = gid; q < cnt; q += 32) {
        float a = kval[q];
        int fb = kcol[q] * RCAP;
        int fn = kcnt[q];
        for (int f0 = gl; f0 < fn; f0 += 32) {
            int i1 = f0 + 8, i2 = f0 + 16, i3 = f0 + 24;
            // 4 independent loads issued before any atomic; masked -> (0,0)
            int2 p0 = pairs[fb + f0];
            int2 p1 = (i1 < fn) ? pairs[fb + i1] : zp;
            int2 p2 = (i2 < fn) ? pairs[fb + i2] : zp;
            int2 p3 = (i3 < fn) ? pairs[fb + i3] : zp;
            unsafeAtomicAdd(&acc[p0.x], a * __int_as_float(p0.y));
            unsafeAtomicAdd(&acc[p1.x], a * __int_as_float(p1.y));
            unsafeAtomicAdd(&acc[p2.x], a * __int_as_float(p2.y));
            unsafeAtomicAdd(&acc[p3.x], a * __int_as_float(p3.y));
        }
    }
    __syncthreads();
    size_t rb = (size_t)i * N_NODES;
    for (int j4 = t; j4 < N_NODES / 4; j4 += 256) {
        float4 v = ((const float4*)acc)[j4];
        ushort4 r;
        r.x = (v.x >= EPS) ? f2bf(v.x) : (unsigned short)0;
        r.y = (v.y >= EPS) ? f2bf(v.y) : (unsigned short)0;
        r.z = (v.z >= EPS) ? f2bf(v.z) : (unsigned short)0;
        r.w = (v.w >= EPS) ? f2bf(v.w) : (unsigned short)0;
        ((ushort4*)(m2 + rb))[j4] = r;
    }
}

// out[i, jb:jb+512] = TH0*P0 + TH1*A + TH2*M2 + TH3*thr(A @ M2)  — fused.
// R3's PASSING kernel (88.6us) + ONE change: the n-prefetch load moved
// BEFORE ISSUE8. Age invariant at each phase top: in-flight = { n-loads
// (OLDER), u-gathers (newer) }. EXTR(n) waits vmcnt(8) -> retires n, leaves
// the gathers in flight; CONSUME8 waits vmcnt(12) -> retires only its own
// gathers. In R3 the n-load came AFTER ISSUE8 (n newer than gathers), so
// EXTR's wait drained the gathers every phase -> full latency exposed.
#define ACC8(uu, aa)                                \
        acc0.x = fmaf(aa, lo16(uu.x), acc0.x);      \
        acc0.y = fmaf(aa, hi16(uu.x), acc0.y);      \
        acc0.z = fmaf(aa, lo16(uu.y), acc0.z);      \
        acc0.w = fmaf(aa, hi16(uu.y), acc0.w);      \
        acc1.x = fmaf(aa, lo16(uu.z), acc1.x);      \
        acc1.y = fmaf(aa, hi16(uu.z), acc1.y);      \
        acc1.z = fmaf(aa, lo16(uu.w), acc1.z);      \
        acc1.w = fmaf(aa, hi16(uu.w), acc1.w);

#define EXTR(E0_, E1_, E2_, E3_, K, A)                                              \
        K##0 = __builtin_amdgcn_readfirstlane(E0_.x); A##0 = __int_as_float(E0_.y); \
        K##1 = __builtin_amdgcn_readfirstlane(E0_.z); A##1 = __int_as_float(E0_.w); \
        K##2 = __builtin_amdgcn_readfirstlane(E1_.x); A##2 = __int_as_float(E1_.y); \
        K##3 = __builtin_amdgcn_readfirstlane(E1_.z); A##3 = __int_as_float(E1_.w); \
        K##4 = __builtin_amdgcn_readfirstlane(E2_.x); A##4 = __int_as_float(E2_.y); \
        K##5 = __builtin_amdgcn_readfirstlane(E2_.z); A##5 = __int_as_float(E2_.w); \
        K##6 = __builtin_amdgcn_readfirstlane(E3_.x); A##6 = __int_as_float(E3_.y); \
        K##7 = __builtin_amdgcn_readfirstlane(E3_.z); A##7 = __int_as_float(E3_.w);

#define ISSUE8(K, U)                                                    \
        U##0 = *(const u32x4*)(m2l + (size_t)K##0 * N_NODES);           \
        U##1 = *(const u32x4*)(m2l + (size_t)K##1 * N_NODES);           \
        U##2 = *(const u32x4*)(m2l + (size_t)K##2 * N_NODES);           \
        U##3 = *(const u32x4*)(m2l + (size_t)K##3 * N_NODES);           \
        U##4 = *(const u32x4*)(m2l + (size_t)K##4 * N_NODES);           \
        U##5 = *(const u32x4*)(m2l + (size_t)K##5 * N_NODES);           \
        U##6 = *(const u32x4*)(m2l + (size_t)K##6 * N_NODES);           \
        U##7 = *(const u32x4*)(m2l + (size_t)K##7 * N_NODES);

#define CONSUME8(U, A)                                                      \
        ACC8(U##0, A##0) ACC8(U##1, A##1) ACC8(U##2, A##2) ACC8(U##3, A##3) \
        ACC8(U##4, A##4) ACC8(U##5, A##5) ACC8(U##6, A##6) ACC8(U##7, A##7)

__global__ __launch_bounds__(128)
void out_kernel(const int* __restrict__ counts, const int2* __restrict__ pairs,
                const unsigned short* __restrict__ m2,
                float* __restrict__ out) {
    __shared__ float ap[2][JTILE];
    int lin = blockIdx.x;
    int tile = lin & 7;
    int jb = tile * JTILE;
    int t = threadIdx.x;
    int w = t >> 6, lane = t & 63;
    int i = 2 * (lin >> 3) + w;
    float* apw = ap[w];
    // TH2 row: issue first (oldest in queue, retires before everything)
    u32x4 um = *(const u32x4*)(m2 + (size_t)i * N_NODES + jb + 8 * lane);
    float4 z4 = make_float4(0.f, 0.f, 0.f, 0.f);
    ((float4*)apw)[lane] = z4;
    ((float4*)apw)[64 + lane] = z4;
    int cnt = min(counts[i * CPAD], RCAP);
    const int2* pi = pairs + i * RCAP;
    // P0 + A scatter into private strip (dups accumulate; cnt excludes pads)
    for (int e = lane; e < cnt; e += 64) {
        int2 p = pi[e];
        int cl = p.x - jb;
        if ((unsigned)cl < (unsigned)JTILE)
            unsafeAtomicAdd(&apw[cl], TH0 + TH1 * __int_as_float(p.y));
    }
    int cnt8 = (cnt + 7) & ~7;
    const unsigned short* m2l = m2 + jb + 8 * lane;
    v4f acc0 = 0.f, acc1 = 0.f;
    const int4* pi4 = (const int4*)pi;

    if (cnt8 > 0) {
        int4 e0, e1, e2, e3, n0, n1, n2, n3;
        int kA0, kA1, kA2, kA3, kA4, kA5, kA6, kA7;
        int kB0, kB1, kB2, kB3, kB4, kB5, kB6, kB7;
        float aA0, aA1, aA2, aA3, aA4, aA5, aA6, aA7;
        float aB0, aB1, aB2, aB3, aB4, aB5, aB6, aB7;
        u32x4 uA0, uA1, uA2, uA3, uA4, uA5, uA6, uA7;
        u32x4 uB0, uB1, uB2, uB3, uB4, uB5, uB6, uB7;

        // prologue: batch0 edges -> extract -> n-load(b1) -> issue uA(b0)
        // invariant established: in-flight { n(b1) OLDER, uA(b0) newer }
        e0 = pi4[0]; e1 = pi4[1]; e2 = pi4[2]; e3 = pi4[3];
        EXTR(e0, e1, e2, e3, kA, aA)          // one-time vmcnt(0) stall
        n0 = pi4[4]; n1 = pi4[5]; n2 = pi4[6]; n3 = pi4[7];
        ISSUE8(kA, uA)

        int e = 0;
        for (;;) {
            // phase A: n holds edges for batch e+8 (older than uA in queue)
            if (e + 8 < cnt8) {
                EXTR(n0, n1, n2, n3, kB, aB)  // vmcnt(8): uA stays in flight
                int nb = min(e + 16, cnt8 - 8) >> 1;  // clamped: stays in memset region
                n0 = pi4[nb]; n1 = pi4[nb + 1]; n2 = pi4[nb + 2]; n3 = pi4[nb + 3];
                ISSUE8(kB, uB)
                CONSUME8(uA, aA)              // vmcnt(12): retires uA only
                e += 8;
            } else { CONSUME8(uA, aA) break; }
            // phase B: symmetric
            if (e + 8 < cnt8) {
                EXTR(n0, n1, n2, n3, kA, aA)
                int nb = min(e + 16, cnt8 - 8) >> 1;
                n0 = pi4[nb]; n1 = pi4[nb + 1]; n2 = pi4[nb + 2]; n3 = pi4[nb + 3];
                ISSUE8(kA, uA)
                CONSUME8(uB, aB)
                e += 8;
            } else { CONSUME8(uB, aB) break; }
        }
    }

    // epilogue: private strip + TH2*m2[i] + TH3*thr(acc)
    float4 p0 = ((const float4*)apw)[2 * lane];
    float4 p1 = ((const float4*)apw)[2 * lane + 1];
    v4f r0, r1;
    r0.x = p0.x + TH2 * lo16(um.x) + TH3 * ((acc0.x >= EPS) ? acc0.x : 0.0f);
    r0.y = p0.y + TH2 * hi16(um.x) + TH3 * ((acc0.y >= EPS) ? acc0.y : 0.0f);
    r0.z = p0.z + TH2 * lo16(um.y) + TH3 * ((acc0.z >= EPS) ? acc0.z : 0.0f);
    r0.w = p0.w + TH2 * hi16(um.y) + TH3 * ((acc0.w >= EPS) ? acc0.w : 0.0f);
    r1.x = p1.x + TH2 * lo16(um.z) + TH3 * ((acc1.x >= EPS) ? acc1.x : 0.0f);
    r1.y = p1.y + TH2 * hi16(um.z) + TH3 * ((acc1.y >= EPS) ? acc1.y : 0.0f);
    r1.z = p1.z + TH2 * lo16(um.w) + TH3 * ((acc1.z >= EPS) ? acc1.z : 0.0f);
    r1.w = p1.w + TH2 * hi16(um.w) + TH3 * ((acc1.w >= EPS) ? acc1.w : 0.0f);
    float* o = out + (size_t)i * N_NODES + jb + 8 * lane;
    __builtin_nontemporal_store(r0, (v4f*)o);
    __builtin_nontemporal_store(r1, (v4f*)(o + 4));
}

extern "C" void kernel_launch(void* const* d_in, const int* in_sizes, int n_in,
                              void* d_out, int out_size, void* d_ws, size_t ws_size,
                              hipStream_t stream) {
    const int* idx = (const int*)d_in[1];     // [2,E] flat: src then dst
    const float* attr = (const float*)d_in[2];
    int E = in_sizes[1] / 2;

    char* ws = (char*)d_ws;
    int*  counts = (int*)(ws);
    int2* pairs  = (int2*)(ws + (256 << 10));
    unsigned short* m2 = (unsigned short*)(ws + (4 << 20));
    float* out   = (float*)d_out;

    // counts (padded) + pairs contiguous: one memset
    (void)hipMemsetAsync(ws, 0,
                         (256 << 10) + N_NODES * RCAP * sizeof(int2), stream);
    scatter_kernel<<<(E + 255) / 256, 256, 0, stream>>>(idx, attr, E, counts, pairs);
    m2_kernel<<<N_NODES, 256, 0, stream>>>(counts, pairs, m2);
    out_kernel<<<(N_NODES / 2) * NTILES, 128, 0, stream>>>(counts, pairs, m2, out);
}

// Round 8
// 187.173 us; speedup vs baseline: 1.2030x; 1.1078x over previous
//
#include <hip/hip_runtime.h>
#include <hip/hip_fp16.h>

#define N_NODES 4096
#define EPS 0.005f
#define TH0 0.4f
#define TH1 0.24f
#define TH2 0.144f
#define TH3 0.0864f
#define JTILE 512
#define NTILES (N_NODES / JTILE)
#define RCAP 80      // fixed per-row slot capacity (mean deg 32, P(>80)~1e-13)
#define CPAD 16      // one counter per 64B line -> no cross-XCD line ping-pong

typedef float v4f __attribute__((ext_vector_type(4)));
typedef unsigned int u32x4 __attribute__((ext_vector_type(4)));

// ws layout (byte offsets):
//   0      counts int[4096*16]         256KB \ one contiguous memset (2816KB)
//   256K   pairs  int2[4096*RCAP]      2.5MB / pads col=0,val=0 -> fma no-op
//   4M     m2     f16[N*N]             32MB dense thresholded A@A
// m2 is FP16 (not bf16): values in [eps, ~8] are exactly representable with
// 2^-11 rel precision (better than bf16), and v_fma_mix_f32 consumes f16
// halves directly -> no unpack VALU op per element (R0-R7 post-mortem: the
// bf16 unpack was ~half of out_kernel's 32us VALU time).

static __device__ __forceinline__ unsigned short f2h(float f) {
    return __half_as_ushort(__float2half(f));  // RNE
}

// one pass: bin edges into fixed-stride packed (col,val) slots
__global__ void scatter_kernel(const int* __restrict__ idx,
                               const float* __restrict__ attr, int E,
                               int* __restrict__ counts, int2* __restrict__ pairs) {
    int e = blockIdx.x * blockDim.x + threadIdx.x;
    if (e < E) {
        int s = idx[e];
        int d = idx[e + E];
        float a = attr[e];
        int pos = atomicAdd(&counts[s * CPAD], 1);
        if (pos < RCAP) pairs[s * RCAP + pos] = make_int2(d, __float_as_int(a));
    }
}

// M2 = thr(A@A) f16. One block per row, full-row 16KB LDS accumulator.
// 32 groups x 8 lanes; fan-out list walked in 32-slot rounds of 4 INDEPENDENT
// loads (chain depth 4 -> 1). Slots in [fn,RCAP) are zero-pads -> no-op adds.
__global__ __launch_bounds__(256)
void m2_kernel(const int* __restrict__ counts, const int2* __restrict__ pairs,
               unsigned short* __restrict__ m2) {
    __shared__ float acc[N_NODES];
    __shared__ int   kcol[RCAP];
    __shared__ float kval[RCAP];
    __shared__ int   kcnt[RCAP];
    int i = blockIdx.x;
    int t = threadIdx.x;
    float4 z = make_float4(0.f, 0.f, 0.f, 0.f);
    for (int j4 = t; j4 < N_NODES / 4; j4 += 256) ((float4*)acc)[j4] = z;
    int cnt = min(counts[i * CPAD], RCAP);
    if (t < cnt) {
        int2 p = pairs[i * RCAP + t];
        kcol[t] = p.x;
        kval[t] = __int_as_float(p.y);
        kcnt[t] = min(counts[p.x * CPAD], RCAP);
    }
    __syncthreads();
    int gid = t >> 3, gl = t & 7;            // 32 groups x 8 lanes
    int2 zp = make_int2(0, 0);
    for (int q = gid; q < cnt; q += 32) {
        float a = kval[q];
        int fb = kcol[q] * RCAP;
        int fn = kcnt[q];
        for (int f0 = gl; f0 < fn; f0 += 32) {
            int i1 = f0 + 8, i2 = f0 + 16, i3 = f0 + 24;
            // 4 independent loads issued before any atomic; masked -> (0,0)
            int2 p0 = pairs[fb + f0];
            int2 p1 = (i1 < fn) ? pairs[fb + i1] : zp;
            int2 p2 = (i2 < fn) ? pairs[fb + i2] : zp;
            int2 p3 = (i3 < fn) ? pairs[fb + i3] : zp;
            unsafeAtomicAdd(&acc[p0.x], a * __int_as_float(p0.y));
            unsafeAtomicAdd(&acc[p1.x], a * __int_as_float(p1.y));
            unsafeAtomicAdd(&acc[p2.x], a * __int_as_float(p2.y));
            unsafeAtomicAdd(&acc[p3.x], a * __int_as_float(p3.y));
        }
    }
    __syncthreads();
    size_t rb = (size_t)i * N_NODES;
    for (int j4 = t; j4 < N_NODES / 4; j4 += 256) {
        float4 v = ((const float4*)acc)[j4];
        ushort4 r;
        r.x = (v.x >= EPS) ? f2h(v.x) : (unsigned short)0;
        r.y = (v.y >= EPS) ? f2h(v.y) : (unsigned short)0;
        r.z = (v.z >= EPS) ? f2h(v.z) : (unsigned short)0;
        r.w = (v.w >= EPS) ? f2h(v.w) : (unsigned short)0;
        ((ushort4*)(m2 + rb))[j4] = r;
    }
}

// out[i, jb:jb+512] = TH0*P0 + TH1*A + TH2*M2 + TH3*thr(A @ M2)  — fused.
// R0 structure EXACTLY (proven 71us: 2 waves/block, %8 XCD pin, private LDS
// strips, 16B gathers) with ONE change: inner product uses v_fma_mix_f32
// (f32 += f32 * f16half), removing the per-element unpack op. 8 VALU/edge
// instead of 16. acc as 8 named scalars for clean asm binding.
#define MIX2(uu_word, aclo, achi, aa)                                          \
    asm("v_fma_mix_f32 %0, %1, %2, %0 op_sel_hi:[0,1,0]"                       \
        : "+v"(aclo) : "v"(aa), "v"(uu_word));                                 \
    asm("v_fma_mix_f32 %0, %1, %2, %0 op_sel:[0,1,0] op_sel_hi:[0,1,0]"        \
        : "+v"(achi) : "v"(aa), "v"(uu_word));

#define MIX8(uu, aa)                                                           \
    MIX2(uu.x, ac0, ac1, aa) MIX2(uu.y, ac2, ac3, aa)                          \
    MIX2(uu.z, ac4, ac5, aa) MIX2(uu.w, ac6, ac7, aa)

__global__ __launch_bounds__(128)
void out_kernel(const int* __restrict__ counts, const int2* __restrict__ pairs,
                const unsigned short* __restrict__ m2,
                float* __restrict__ out) {
    __shared__ float ap[2][JTILE];
    int lin = blockIdx.x;
    int tile = lin & 7;
    int jb = tile * JTILE;
    int t = threadIdx.x;
    int w = t >> 6, lane = t & 63;
    int i = 2 * (lin >> 3) + w;
    float* apw = ap[w];
    ((float4*)apw)[lane] = make_float4(0.f, 0.f, 0.f, 0.f);
    ((float4*)apw)[64 + lane] = make_float4(0.f, 0.f, 0.f, 0.f);
    int cnt = min(counts[i * CPAD], RCAP);
    const int2* pi = pairs + i * RCAP;
    // P0 + A scatter into private strip (dups accumulate; cnt excludes pads)
    for (int e = lane; e < cnt; e += 64) {
        int2 p = pi[e];
        int cl = p.x - jb;
        if ((unsigned)cl < (unsigned)JTILE)
            unsafeAtomicAdd(&apw[cl], TH0 + TH1 * __int_as_float(p.y));
    }
    // dense gather over neighbors' m2 rows, 8 per iteration, 16B/lane
    int cnt8 = (cnt + 7) & ~7;
    const unsigned short* m2l = m2 + jb + 8 * lane;
    float ac0 = 0.f, ac1 = 0.f, ac2 = 0.f, ac3 = 0.f;
    float ac4 = 0.f, ac5 = 0.f, ac6 = 0.f, ac7 = 0.f;
    for (int e = 0; e < cnt8; e += 8) {
        int4 q01 = *(const int4*)(pi + e);
        int4 q23 = *(const int4*)(pi + e + 2);
        int4 q45 = *(const int4*)(pi + e + 4);
        int4 q67 = *(const int4*)(pi + e + 6);
        int k0 = __builtin_amdgcn_readfirstlane(q01.x);
        int k1 = __builtin_amdgcn_readfirstlane(q01.z);
        int k2 = __builtin_amdgcn_readfirstlane(q23.x);
        int k3 = __builtin_amdgcn_readfirstlane(q23.z);
        int k4 = __builtin_amdgcn_readfirstlane(q45.x);
        int k5 = __builtin_amdgcn_readfirstlane(q45.z);
        int k6 = __builtin_amdgcn_readfirstlane(q67.x);
        int k7 = __builtin_amdgcn_readfirstlane(q67.z);
        float a0 = __int_as_float(q01.y), a1 = __int_as_float(q01.w);
        float a2 = __int_as_float(q23.y), a3 = __int_as_float(q23.w);
        float a4 = __int_as_float(q45.y), a5 = __int_as_float(q45.w);
        float a6 = __int_as_float(q67.y), a7 = __int_as_float(q67.w);
        u32x4 u0 = *(const u32x4*)(m2l + (size_t)k0 * N_NODES);
        u32x4 u1 = *(const u32x4*)(m2l + (size_t)k1 * N_NODES);
        u32x4 u2 = *(const u32x4*)(m2l + (size_t)k2 * N_NODES);
        u32x4 u3 = *(const u32x4*)(m2l + (size_t)k3 * N_NODES);
        u32x4 u4 = *(const u32x4*)(m2l + (size_t)k4 * N_NODES);
        u32x4 u5 = *(const u32x4*)(m2l + (size_t)k5 * N_NODES);
        u32x4 u6 = *(const u32x4*)(m2l + (size_t)k6 * N_NODES);
        u32x4 u7 = *(const u32x4*)(m2l + (size_t)k7 * N_NODES);
        MIX8(u0, a0) MIX8(u1, a1) MIX8(u2, a2) MIX8(u3, a3)
        MIX8(u4, a4) MIX8(u5, a5) MIX8(u6, a6) MIX8(u7, a7)
    }
    // epilogue: private strip + TH2*m2[i] + TH3*thr(acc)
    u32x4 um = *(const u32x4*)(m2 + (size_t)i * N_NODES + jb + 8 * lane);
    unsigned ux = um.x, uy = um.y, uz = um.z, uw = um.w;
    __half2 hx = *(__half2*)&ux, hy = *(__half2*)&uy;
    __half2 hz = *(__half2*)&uz, hw = *(__half2*)&uw;
    float4 p0 = ((const float4*)apw)[2 * lane];
    float4 p1 = ((const float4*)apw)[2 * lane + 1];
    v4f r0, r1;
    r0.x = p0.x + TH2 * __low2float(hx)  + TH3 * ((ac0 >= EPS) ? ac0 : 0.0f);
    r0.y = p0.y + TH2 * __high2float(hx) + TH3 * ((ac1 >= EPS) ? ac1 : 0.0f);
    r0.z = p0.z + TH2 * __low2float(hy)  + TH3 * ((ac2 >= EPS) ? ac2 : 0.0f);
    r0.w = p0.w + TH2 * __high2float(hy) + TH3 * ((ac3 >= EPS) ? ac3 : 0.0f);
    r1.x = p1.x + TH2 * __low2float(hz)  + TH3 * ((ac4 >= EPS) ? ac4 : 0.0f);
    r1.y = p1.y + TH2 * __high2float(hz) + TH3 * ((ac5 >= EPS) ? ac5 : 0.0f);
    r1.z = p1.z + TH2 * __low2float(hw)  + TH3 * ((ac6 >= EPS) ? ac6 : 0.0f);
    r1.w = p1.w + TH2 * __high2float(hw) + TH3 * ((ac7 >= EPS) ? ac7 : 0.0f);
    float* o = out + (size_t)i * N_NODES + jb + 8 * lane;
    __builtin_nontemporal_store(r0, (v4f*)o);
    __builtin_nontemporal_store(r1, (v4f*)(o + 4));
}

extern "C" void kernel_launch(void* const* d_in, const int* in_sizes, int n_in,
                              void* d_out, int out_size, void* d_ws, size_t ws_size,
                              hipStream_t stream) {
    const int* idx = (const int*)d_in[1];     // [2,E] flat: src then dst
    const float* attr = (const float*)d_in[2];
    int E = in_sizes[1] / 2;

    char* ws = (char*)d_ws;
    int*  counts = (int*)(ws);
    int2* pairs  = (int2*)(ws + (256 << 10));
    unsigned short* m2 = (unsigned short*)(ws + (4 << 20));
    float* out   = (float*)d_out;

    // counts (padded) + pairs contiguous: one memset
    (void)hipMemsetAsync(ws, 0,
                         (256 << 10) + N_NODES * RCAP * sizeof(int2), stream);
    scatter_kernel<<<(E + 255) / 256, 256, 0, stream>>>(idx, attr, E, counts, pairs);
    m2_kernel<<<N_NODES, 256, 0, stream>>>(counts, pairs, m2);
    out_kernel<<<(N_NODES / 2) * NTILES, 128, 0, stream>>>(counts, pairs, m2, out);
}